// Round 1
// baseline (572.453 us; speedup 1.0000x reference)
//
#include <hip/hip_runtime.h>

// TopDownProjector: volume [B=2, C=1, H=512, W=512, D=256] f32, depth innermost.
// Per column: first non-zero scanning from d=D-1 downward.
//   height_field[col] = hit index (0 if empty)
//   seg_map[col]      = volume[col, hit] (0 if empty)
// d_out = [height_field (524288 f32) | seg_map (524288 f32)]
//
// Labels uniform in [0,9) => P(zero)=1/9; top float4 resolves ~99.98% of
// columns, so the scan loop is ~1 iteration. One 128B line per column is
// the HBM traffic floor (~64 MiB fetch).

#define DDEPTH 256

__global__ __launch_bounds__(256)
void TopDownProjector_82806969467611_kernel(const float* __restrict__ vol,
                                            float* __restrict__ height,
                                            float* __restrict__ seg,
                                            int ncols) {
    int col = blockIdx.x * blockDim.x + threadIdx.x;
    if (col >= ncols) return;

    const float4* base = (const float4*)(vol + (size_t)col * DDEPTH);

    float h = 0.0f, s = 0.0f;
    // Scan from the top quad (indices 252..255) downward.
    #pragma unroll 1
    for (int q = DDEPTH / 4 - 1; q >= 0; --q) {
        float4 v = base[q];
        if (v.x != 0.0f || v.y != 0.0f || v.z != 0.0f || v.w != 0.0f) {
            int idx;
            float val;
            if (v.w != 0.0f)      { idx = q * 4 + 3; val = v.w; }
            else if (v.z != 0.0f) { idx = q * 4 + 2; val = v.z; }
            else if (v.y != 0.0f) { idx = q * 4 + 1; val = v.y; }
            else                  { idx = q * 4 + 0; val = v.x; }
            h = (float)idx;
            s = val;
            break;
        }
    }

    height[col] = h;
    seg[col]    = s;
}

extern "C" void kernel_launch(void* const* d_in, const int* in_sizes, int n_in,
                              void* d_out, int out_size, void* d_ws, size_t ws_size,
                              hipStream_t stream) {
    const float* vol = (const float*)d_in[0];
    float* out = (float*)d_out;

    int ncols = in_sizes[0] / DDEPTH;      // 524288
    float* height = out;                   // first output plane
    float* seg    = out + ncols;           // second output plane

    int block = 256;
    int grid = (ncols + block - 1) / block;
    TopDownProjector_82806969467611_kernel<<<grid, block, 0, stream>>>(
        vol, height, seg, ncols);
}